// Round 10
// baseline (23.071 us; speedup 1.0000x reference)
//
#include <hip/hip_runtime.h>

// CompositeLoss: boundary-weighted BCE + Dice over (32,1,512,512)
// pred: float32 uniform [0,1), target: int32 binary {0,1}
// out: [total, bce, dice] float32
//
// R10 = R3 compute loop VERBATIM (best measured: 21.85us, absmax 0.0)
//     + R4 reduction plumbing VERBATIM (float4 partials, 1024-thr finalize).
// Ledger: scratch->regs -96us; shuffle halos -5.5us; VMEM count/MLP/strip
// shape: null (R5/R7/R9); per-block device fence: +65..125us (R6/R8) --
// single-kernel finalize is structurally dead on non-coherent XCD L2s.

#define BB 32
#define HH 512
#define WW 512
#define N_TOTAL (BB * HH * WW)
#define SEG 8
#define W8 (WW / SEG)            // 64 segments per row -> one wave per row
#define NSEG (BB * HH * W8)      // 1,048,576
#define NBLK 2048

__global__ __launch_bounds__(256) void loss_main_kernel(
        const float* __restrict__ pred,
        const int* __restrict__ target,
        float4* __restrict__ partials) {
    float wbce = 0.f, inter = 0.f, sp = 0.f;
    int st_i = 0;

    const int lane = threadIdx.x & 63;
    const int stride = gridDim.x * blockDim.x;   // 524288 -> exactly 2 iters
    for (int seg = blockIdx.x * blockDim.x + threadIdx.x; seg < NSEG;
         seg += stride) {
        const int w0 = (seg & (W8 - 1)) << 3;    // == lane*8
        const int h  = (seg >> 6) & (HH - 1);
        const int b  = seg >> 15;

        const size_t rowbase = ((size_t)(b * HH + h)) * WW;

        const float4 p0 = *(const float4*)(pred + rowbase + w0);
        const float4 p1 = *(const float4*)(pred + rowbase + w0 + 4);

        const int* rowC = target + rowbase;                       // row h
        const int* rowU = (h > 0)      ? rowC - WW : rowC;        // row h-1 (clamped)
        const int* rowD = (h < HH - 1) ? rowC + WW : rowC;        // row h+1 (clamped)

        const int4 uA = *(const int4*)(rowU + w0);
        const int4 uB = *(const int4*)(rowU + w0 + 4);
        const int4 cA = *(const int4*)(rowC + w0);
        const int4 cB = *(const int4*)(rowC + w0 + 4);
        const int4 dA = *(const int4*)(rowD + w0);
        const int4 dB = *(const int4*)(rowD + w0 + 4);

        // vertical OR / AND (separable 3x3 morphology), all named
        const int o0 = uA.x | cA.x | dA.x,  n0 = uA.x & cA.x & dA.x;
        const int o1 = uA.y | cA.y | dA.y,  n1 = uA.y & cA.y & dA.y;
        const int o2 = uA.z | cA.z | dA.z,  n2 = uA.z & cA.z & dA.z;
        const int o3 = uA.w | cA.w | dA.w,  n3 = uA.w & cA.w & dA.w;
        const int o4 = uB.x | cB.x | dB.x,  n4 = uB.x & cB.x & dB.x;
        const int o5 = uB.y | cB.y | dB.y,  n5 = uB.y & cB.y & dB.y;
        const int o6 = uB.z | cB.z | dB.z,  n6 = uB.z & cB.z & dB.z;
        const int o7 = uB.w | cB.w | dB.w,  n7 = uB.w & cB.w & dB.w;

        // halo columns via shuffle (wave spans the whole row; w8 == lane)
        int oL = __shfl_up(o7, 1);
        int nL = __shfl_up(n7, 1);
        int oR = __shfl_down(o0, 1);
        int nR = __shfl_down(n0, 1);
        if (lane == 0)  { oL = o0; nL = n0; }   // clamp col -1 -> col 0
        if (lane == 63) { oR = o7; nR = n7; }   // clamp col 512 -> col 511

        // horizontal window -> boundary flag per pixel
        const int e0 = (oL | o0 | o1) != (nL & n0 & n1);
        const int e1 = (o0 | o1 | o2) != (n0 & n1 & n2);
        const int e2 = (o1 | o2 | o3) != (n1 & n2 & n3);
        const int e3 = (o2 | o3 | o4) != (n2 & n3 & n4);
        const int e4 = (o3 | o4 | o5) != (n3 & n4 & n5);
        const int e5 = (o4 | o5 | o6) != (n4 & n5 & n6);
        const int e6 = (o5 | o6 | o7) != (n5 & n6 & n7);
        const int e7 = (o6 | o7 | oR) != (n6 & n7 & nR);

#define ACC(T, P, E)                                                   \
        {                                                              \
            const float pc = fminf(fmaxf((P), 1e-7f), 1.0f - 1e-7f);   \
            const float x  = (T) ? pc : (1.0f - pc);                   \
            wbce += ((E) ? 3.0f : 1.0f) * (-__logf(x));                \
            sp += (P);                                                 \
            if (T) inter += (P);                                       \
            st_i += (T);                                               \
        }

        ACC(cA.x, p0.x, e0); ACC(cA.y, p0.y, e1);
        ACC(cA.z, p0.z, e2); ACC(cA.w, p0.w, e3);
        ACC(cB.x, p1.x, e4); ACC(cB.y, p1.y, e5);
        ACC(cB.z, p1.z, e6); ACC(cB.w, p1.w, e7);
#undef ACC
    }

    // wave (64-lane) shuffle reduction
    float st = (float)st_i;
    #pragma unroll
    for (int off = 32; off > 0; off >>= 1) {
        wbce  += __shfl_down(wbce,  off);
        inter += __shfl_down(inter, off);
        sp    += __shfl_down(sp,    off);
        st    += __shfl_down(st,    off);
    }

    __shared__ float smem[4][4];
    const int wave = threadIdx.x >> 6;
    if ((threadIdx.x & 63) == 0) {
        smem[wave][0] = wbce; smem[wave][1] = inter;
        smem[wave][2] = sp;   smem[wave][3] = st;
    }
    __syncthreads();
    if (threadIdx.x == 0) {
        float s0 = 0, s1 = 0, s2 = 0, s3 = 0;
        #pragma unroll
        for (int wv = 0; wv < 4; ++wv) {
            s0 += smem[wv][0]; s1 += smem[wv][1];
            s2 += smem[wv][2]; s3 += smem[wv][3];
        }
        partials[blockIdx.x] = make_float4(s0, s1, s2, s3);
    }
}

__global__ __launch_bounds__(1024) void finalize_kernel(
        const float4* __restrict__ partials, float* __restrict__ out) {
    double a0 = 0, a1 = 0, a2 = 0, a3 = 0;
    #pragma unroll
    for (int k = 0; k < NBLK / 1024; ++k) {
        const float4 p = partials[k * 1024 + threadIdx.x];
        a0 += p.x; a1 += p.y; a2 += p.z; a3 += p.w;
    }
    #pragma unroll
    for (int off = 32; off > 0; off >>= 1) {
        a0 += __shfl_down(a0, off);
        a1 += __shfl_down(a1, off);
        a2 += __shfl_down(a2, off);
        a3 += __shfl_down(a3, off);
    }
    __shared__ double smem[16][4];
    const int wave = threadIdx.x >> 6;
    if ((threadIdx.x & 63) == 0) {
        smem[wave][0] = a0; smem[wave][1] = a1;
        smem[wave][2] = a2; smem[wave][3] = a3;
    }
    __syncthreads();
    if (threadIdx.x == 0) {
        double s0 = 0, s1 = 0, s2 = 0, s3 = 0;
        #pragma unroll
        for (int wv = 0; wv < 16; ++wv) {
            s0 += smem[wv][0]; s1 += smem[wv][1];
            s2 += smem[wv][2]; s3 += smem[wv][3];
        }
        const double bce = s0 / (double)N_TOTAL;
        const double dice_coef = (2.0 * s1 + 1e-6) / (s2 + s3 + 1e-6);
        const double dice = 1.0 - dice_coef;
        const double total = 0.5 * bce + 0.5 * dice;
        out[0] = (float)total;
        out[1] = (float)bce;
        out[2] = (float)dice;
    }
}

extern "C" void kernel_launch(void* const* d_in, const int* in_sizes, int n_in,
                              void* d_out, int out_size, void* d_ws, size_t ws_size,
                              hipStream_t stream) {
    const float* pred  = (const float*)d_in[0];
    const int* target  = (const int*)d_in[1];
    float* out = (float*)d_out;
    float4* partials = (float4*)d_ws;   // NBLK float4 = 32 KB

    loss_main_kernel<<<NBLK, 256, 0, stream>>>(pred, target, partials);
    finalize_kernel<<<1, 1024, 0, stream>>>(partials, out);
}

// Round 11
// 21.249 us; speedup vs baseline: 1.0858x; 1.0858x over previous
//
#include <hip/hip_runtime.h>

// CompositeLoss: boundary-weighted BCE + Dice over (32,1,512,512)
// pred: float32 uniform [0,1), target: int32 binary {0,1}
// out: [total, bce, dice] float32
//
// R11 = R10 compute/reduction VERBATIM + two memory-path-only changes:
//  (1) T1 XCD-contiguous block remap (bijective: 2048 = 8 XCD x 256):
//      adjacent row-strips (which share halo rows) stay on one XCD's L2
//      instead of round-robining across XCDs and bouncing through L3.
//  (2) int32 offset addressing: all offsets are 32-bit from the array base;
//      iter-2 = iter-1 offsets + 16 images (compile-time const -> SGPR base),
//      so the compiler reuses voffsets and folds +16B into offset: imms.
// Ledger: scratch->regs -96us; shuffle halos -5.5us; VMEM count/MLP/
// persistence/strip shape: null (R5/R7/R9); per-block device fence:
// +65..125us (R6/R8).

#define BB 32
#define HH 512
#define WW 512
#define N_TOTAL (BB * HH * WW)
#define NBLK 2048

__global__ __launch_bounds__(256) void loss_main_kernel(
        const float* __restrict__ pred,
        const int* __restrict__ target,
        float4* __restrict__ partials) {
    const int lane = threadIdx.x & 63;

    // ---- (1) XCD-contiguous bijective remap: work id for this block ----
    const int bid = ((int)blockIdx.x & 7) * (NBLK / 8) + ((int)blockIdx.x >> 3);

    // ---- (2) int32 seg decode, once; iter 2 adds a compile-time const ----
    const int seg = bid * 256 + (int)threadIdx.x;   // 0..524287
    const int w0  = (seg & 63) << 3;                // == lane*8
    const int h   = (seg >> 6) & (HH - 1);
    const int b   = seg >> 15;                      // 0..15 (iter1)

    const int offC = (b * HH + h) * WW + w0;        // element offset, < 2^23
    const int dU = (h > 0)      ? -WW : 0;          // clamped row deltas
    const int dD = (h < HH - 1) ?  WW : 0;

    float wbce = 0.f, inter = 0.f, sp = 0.f;
    int st_i = 0;

    #pragma unroll
    for (int it = 0; it < 2; ++it) {
        const int base = offC + it * (16 * HH * WW);   // iter2: image b+16

        const float* pp = pred + base;
        const int*   tC = target + base;
        const int*   tU = target + base + dU;
        const int*   tD = target + base + dD;

        const float4 p0 = *(const float4*)(pp);
        const float4 p1 = *(const float4*)(pp + 4);

        const int4 uA = *(const int4*)(tU);
        const int4 uB = *(const int4*)(tU + 4);
        const int4 cA = *(const int4*)(tC);
        const int4 cB = *(const int4*)(tC + 4);
        const int4 dA = *(const int4*)(tD);
        const int4 dB = *(const int4*)(tD + 4);

        // vertical OR / AND (separable 3x3 morphology), all named
        const int o0 = uA.x | cA.x | dA.x,  n0 = uA.x & cA.x & dA.x;
        const int o1 = uA.y | cA.y | dA.y,  n1 = uA.y & cA.y & dA.y;
        const int o2 = uA.z | cA.z | dA.z,  n2 = uA.z & cA.z & dA.z;
        const int o3 = uA.w | cA.w | dA.w,  n3 = uA.w & cA.w & dA.w;
        const int o4 = uB.x | cB.x | dB.x,  n4 = uB.x & cB.x & dB.x;
        const int o5 = uB.y | cB.y | dB.y,  n5 = uB.y & cB.y & dB.y;
        const int o6 = uB.z | cB.z | dB.z,  n6 = uB.z & cB.z & dB.z;
        const int o7 = uB.w | cB.w | dB.w,  n7 = uB.w & cB.w & dB.w;

        // halo columns via shuffle (wave spans the whole row; w8 == lane)
        int oL = __shfl_up(o7, 1);
        int nL = __shfl_up(n7, 1);
        int oR = __shfl_down(o0, 1);
        int nR = __shfl_down(n0, 1);
        if (lane == 0)  { oL = o0; nL = n0; }   // clamp col -1 -> col 0
        if (lane == 63) { oR = o7; nR = n7; }   // clamp col 512 -> col 511

        // horizontal window -> boundary flag per pixel
        const int e0 = (oL | o0 | o1) != (nL & n0 & n1);
        const int e1 = (o0 | o1 | o2) != (n0 & n1 & n2);
        const int e2 = (o1 | o2 | o3) != (n1 & n2 & n3);
        const int e3 = (o2 | o3 | o4) != (n2 & n3 & n4);
        const int e4 = (o3 | o4 | o5) != (n3 & n4 & n5);
        const int e5 = (o4 | o5 | o6) != (n4 & n5 & n6);
        const int e6 = (o5 | o6 | o7) != (n5 & n6 & n7);
        const int e7 = (o6 | o7 | oR) != (n6 & n7 & nR);

#define ACC(T, P, E)                                                   \
        {                                                              \
            const float pc = fminf(fmaxf((P), 1e-7f), 1.0f - 1e-7f);   \
            const float x  = (T) ? pc : (1.0f - pc);                   \
            wbce += ((E) ? 3.0f : 1.0f) * (-__logf(x));                \
            sp += (P);                                                 \
            if (T) inter += (P);                                       \
            st_i += (T);                                               \
        }

        ACC(cA.x, p0.x, e0); ACC(cA.y, p0.y, e1);
        ACC(cA.z, p0.z, e2); ACC(cA.w, p0.w, e3);
        ACC(cB.x, p1.x, e4); ACC(cB.y, p1.y, e5);
        ACC(cB.z, p1.z, e6); ACC(cB.w, p1.w, e7);
#undef ACC
    }

    // wave (64-lane) shuffle reduction
    float st = (float)st_i;
    #pragma unroll
    for (int off = 32; off > 0; off >>= 1) {
        wbce  += __shfl_down(wbce,  off);
        inter += __shfl_down(inter, off);
        sp    += __shfl_down(sp,    off);
        st    += __shfl_down(st,    off);
    }

    __shared__ float smem[4][4];
    const int wave = threadIdx.x >> 6;
    if ((threadIdx.x & 63) == 0) {
        smem[wave][0] = wbce; smem[wave][1] = inter;
        smem[wave][2] = sp;   smem[wave][3] = st;
    }
    __syncthreads();
    if (threadIdx.x == 0) {
        float s0 = 0, s1 = 0, s2 = 0, s3 = 0;
        #pragma unroll
        for (int wv = 0; wv < 4; ++wv) {
            s0 += smem[wv][0]; s1 += smem[wv][1];
            s2 += smem[wv][2]; s3 += smem[wv][3];
        }
        partials[blockIdx.x] = make_float4(s0, s1, s2, s3);
    }
}

__global__ __launch_bounds__(1024) void finalize_kernel(
        const float4* __restrict__ partials, float* __restrict__ out) {
    double a0 = 0, a1 = 0, a2 = 0, a3 = 0;
    #pragma unroll
    for (int k = 0; k < NBLK / 1024; ++k) {
        const float4 p = partials[k * 1024 + threadIdx.x];
        a0 += p.x; a1 += p.y; a2 += p.z; a3 += p.w;
    }
    #pragma unroll
    for (int off = 32; off > 0; off >>= 1) {
        a0 += __shfl_down(a0, off);
        a1 += __shfl_down(a1, off);
        a2 += __shfl_down(a2, off);
        a3 += __shfl_down(a3, off);
    }
    __shared__ double smem[16][4];
    const int wave = threadIdx.x >> 6;
    if ((threadIdx.x & 63) == 0) {
        smem[wave][0] = a0; smem[wave][1] = a1;
        smem[wave][2] = a2; smem[wave][3] = a3;
    }
    __syncthreads();
    if (threadIdx.x == 0) {
        double s0 = 0, s1 = 0, s2 = 0, s3 = 0;
        #pragma unroll
        for (int wv = 0; wv < 16; ++wv) {
            s0 += smem[wv][0]; s1 += smem[wv][1];
            s2 += smem[wv][2]; s3 += smem[wv][3];
        }
        const double bce = s0 / (double)N_TOTAL;
        const double dice_coef = (2.0 * s1 + 1e-6) / (s2 + s3 + 1e-6);
        const double dice = 1.0 - dice_coef;
        const double total = 0.5 * bce + 0.5 * dice;
        out[0] = (float)total;
        out[1] = (float)bce;
        out[2] = (float)dice;
    }
}

extern "C" void kernel_launch(void* const* d_in, const int* in_sizes, int n_in,
                              void* d_out, int out_size, void* d_ws, size_t ws_size,
                              hipStream_t stream) {
    const float* pred  = (const float*)d_in[0];
    const int* target  = (const int*)d_in[1];
    float* out = (float*)d_out;
    float4* partials = (float4*)d_ws;   // NBLK float4 = 32 KB

    loss_main_kernel<<<NBLK, 256, 0, stream>>>(pred, target, partials);
    finalize_kernel<<<1, 1024, 0, stream>>>(partials, out);
}